// Round 1
// baseline (3605.807 us; speedup 1.0000x reference)
//
#include <hip/hip_runtime.h>
#include <hip/hip_cooperative_groups.h>

namespace cg = cooperative_groups;

#define BATCH 32
#define HH 256
#define WW 256
#define PLANE (HH * WW)         // 65536
#define TOTAL (BATCH * PLANE)   // 2097152
#define NSTEPS 31               // t in [0,32) -> max 31 active steps; extras are identity

__global__ __launch_bounds__(256, 4)
void rd_fkpp_kernel(const float* __restrict__ u_in,
                    const float* __restrict__ params,
                    const int* __restrict__ t,
                    float* __restrict__ out,
                    float* __restrict__ ws)
{
    cg::grid_group grid = cg::this_grid();
    const int tid = blockIdx.x * blockDim.x + threadIdx.x;
    const int nthreads = gridDim.x * blockDim.x;
    const int nchunks = TOTAL / 4;  // 524288 float4 chunks

    for (int s = 0; s < NSTEPS; ++s) {
        // Step s reads R[s], writes W[s].  W[s] = (s odd) ? ws : out, so the
        // final step (s=30, even) writes d_out.  R[0] = u_in, R[s] = W[s-1].
        const float* __restrict__ src = (s == 0) ? u_in : ((s & 1) ? out : ws);
        float* __restrict__ dst = (s & 1) ? ws : out;

        for (int c = tid; c < nchunks; c += nthreads) {
            const int e   = c << 2;           // base element index (j multiple of 4)
            const int b   = e >> 16;          // batch
            const int rem = e & (PLANE - 1);
            const int i   = rem >> 8;         // row
            const int j   = rem & (WW - 1);   // col (0,4,...,252)

            const float4 uc = *reinterpret_cast<const float4*>(src + e);
            float4 up = make_float4(0.f, 0.f, 0.f, 0.f);
            float4 dn = make_float4(0.f, 0.f, 0.f, 0.f);
            if (i > 0)      up = *reinterpret_cast<const float4*>(src + e - WW);
            if (i < HH - 1) dn = *reinterpret_cast<const float4*>(src + e + WW);
            const float lf = (j > 0)       ? src[e - 1] : 0.0f;
            const float rt = (j + 4 < WW)  ? src[e + 4] : 0.0f;

            const float* pD = params + (size_t)b * 2 * PLANE + rem;
            const float4 Dv = *reinterpret_cast<const float4*>(pD);
            const float4 Rv = *reinterpret_cast<const float4*>(pD + PLANE);

            const bool active = (t[b] > s);

            // 5-point Laplacian with zero ('SAME') padding
            const float lap0 = up.x + dn.x + lf   + uc.y - 4.0f * uc.x;
            const float lap1 = up.y + dn.y + uc.x + uc.z - 4.0f * uc.y;
            const float lap2 = up.z + dn.z + uc.y + uc.w - 4.0f * uc.z;
            const float lap3 = up.w + dn.w + uc.z + rt   - 4.0f * uc.w;

            float4 un;
            {
                const float f0 = Dv.x * lap0 + Rv.x * uc.x * (1.0f - uc.x);
                const float f1 = Dv.y * lap1 + Rv.y * uc.y * (1.0f - uc.y);
                const float f2 = Dv.z * lap2 + Rv.z * uc.z * (1.0f - uc.z);
                const float f3 = Dv.w * lap3 + Rv.w * uc.w * (1.0f - uc.w);
                un.x = active ? uc.x + f0 : uc.x;
                un.y = active ? uc.y + f1 : uc.y;
                un.z = active ? uc.z + f2 : uc.z;
                un.w = active ? uc.w + f3 : uc.w;
            }
            // clip(u, 0, 1) — applied every step like the reference body
            un.x = fminf(fmaxf(un.x, 0.0f), 1.0f);
            un.y = fminf(fmaxf(un.y, 0.0f), 1.0f);
            un.z = fminf(fmaxf(un.z, 0.0f), 1.0f);
            un.w = fminf(fmaxf(un.w, 0.0f), 1.0f);

            *reinterpret_cast<float4*>(dst + e) = un;
        }
        grid.sync();
    }
}

extern "C" void kernel_launch(void* const* d_in, const int* in_sizes, int n_in,
                              void* d_out, int out_size, void* d_ws, size_t ws_size,
                              hipStream_t stream) {
    (void)in_sizes; (void)n_in; (void)out_size; (void)ws_size;
    const float* u      = (const float*)d_in[0];
    const float* params = (const float*)d_in[1];
    const int*   t      = (const int*)d_in[2];
    float*       out    = (float*)d_out;
    float*       ws     = (float*)d_ws;

    void* args[] = { (void*)&u, (void*)&params, (void*)&t, (void*)&out, (void*)&ws };
    hipLaunchCooperativeKernel((const void*)rd_fkpp_kernel,
                               dim3(1024), dim3(256), args, 0, stream);
}

// Round 2
// 60.062 us; speedup vs baseline: 60.0348x; 60.0348x over previous
//
#include <hip/hip_runtime.h>

#define HH 256
#define WW 256
#define PLANE (HH * WW)          // 65536
#define CORE 32                  // output rows per strip
#define HALO 8                   // temporal halo rows (>= steps per launch)
#define SLAB 48                  // CORE + 2*HALO
#define NW 16                    // waves per block (1024 threads)
#define RPW 3                    // slab rows per wave (SLAB / NW)

// One block = one 48-row slab of one image (32-row core + 8-row halo).
// u, D, rho live in registers (3 rows x 4 cols per thread).
// Horizontal neighbors: wave-internal __shfl (a wave owns a full 256-col row).
// Vertical neighbors across waves: LDS row buffers + __syncthreads.
// Runs k steps locally; halo >= k keeps the core rows exact.
__global__ __launch_bounds__(1024, 4)
void rd_group_kernel(const float* __restrict__ uin,
                     const float* __restrict__ params,
                     const int* __restrict__ t,
                     float* __restrict__ uout,
                     int base, int k)
{
    __shared__ float4 vt[NW][64];   // each wave's top row (dr=0)
    __shared__ float4 vb[NW][64];   // each wave's bottom row (dr=2)

    const int blk   = blockIdx.x;
    const int b     = blk >> 3;          // image index
    const int strip = blk & 7;
    const int r0    = strip * CORE;
    const int w     = threadIdx.x >> 6;  // wave = row-group, 0..15
    const int lane  = threadIdx.x & 63;  // lane = col-group (4 cols each)
    const int c0    = lane << 2;

    const int growbase = r0 - HALO + RPW * w;  // global row of this thread's dr=0

    // steps this block actually runs in this launch: min(k, max(0, t[b]-base))
    int ls = t[b] - base;
    ls = ls < 0 ? 0 : (ls > k ? k : ls);

    float u[RPW][4], pD[RPW][4], pR[RPW][4];
    bool inimg[RPW];

    const size_t ubase = (size_t)b * PLANE;
    const size_t pbase = (size_t)b * 2 * PLANE;

    #pragma unroll
    for (int dr = 0; dr < RPW; ++dr) {
        const int grow = growbase + dr;
        inimg[dr] = (grow >= 0) && (grow < HH);
        if (inimg[dr]) {
            const float4 uu = *reinterpret_cast<const float4*>(uin + ubase + (size_t)grow * WW + c0);
            const float4 dd = *reinterpret_cast<const float4*>(params + pbase + (size_t)grow * WW + c0);
            const float4 rr = *reinterpret_cast<const float4*>(params + pbase + PLANE + (size_t)grow * WW + c0);
            u[dr][0] = uu.x; u[dr][1] = uu.y; u[dr][2] = uu.z; u[dr][3] = uu.w;
            pD[dr][0] = dd.x; pD[dr][1] = dd.y; pD[dr][2] = dd.z; pD[dr][3] = dd.w;
            pR[dr][0] = rr.x; pR[dr][1] = rr.y; pR[dr][2] = rr.z; pR[dr][3] = rr.w;
        } else {
            #pragma unroll
            for (int c = 0; c < 4; ++c) { u[dr][c] = 0.f; pD[dr][c] = 0.f; pR[dr][c] = 0.f; }
        }
    }

    for (int s = 0; s < ls; ++s) {
        // publish wave-boundary rows
        vt[w][lane] = make_float4(u[0][0], u[0][1], u[0][2], u[0][3]);
        vb[w][lane] = make_float4(u[RPW-1][0], u[RPW-1][1], u[RPW-1][2], u[RPW-1][3]);
        __syncthreads();

        float upr[4] = {0.f, 0.f, 0.f, 0.f};
        float dnr[4] = {0.f, 0.f, 0.f, 0.f};
        if (w > 0)      { float4 v = vb[w-1][lane]; upr[0]=v.x; upr[1]=v.y; upr[2]=v.z; upr[3]=v.w; }
        if (w < NW - 1) { float4 v = vt[w+1][lane]; dnr[0]=v.x; dnr[1]=v.y; dnr[2]=v.z; dnr[3]=v.w; }

        float nu[RPW][4];
        #pragma unroll
        for (int dr = 0; dr < RPW; ++dr) {
            // horizontal neighbors across lanes (a wave spans the full row width;
            // lane 0 / lane 63 edges are the image border -> zero pad)
            float lf = __shfl_up(u[dr][3], 1);
            if (lane == 0)  lf = 0.f;
            float rt = __shfl_down(u[dr][0], 1);
            if (lane == 63) rt = 0.f;

            #pragma unroll
            for (int c = 0; c < 4; ++c) {
                const float upv = dr ? u[dr-1][c] : upr[c];
                const float dnv = (dr < RPW - 1) ? u[dr+1][c] : dnr[c];
                const float lv  = c ? u[dr][c-1] : lf;
                const float rv  = (c < 3) ? u[dr][c+1] : rt;
                const float uc  = u[dr][c];
                const float lap = upv + dnv + lv + rv - 4.0f * uc;
                float un = uc + pD[dr][c] * lap + pR[dr][c] * (uc * (1.0f - uc));
                un = fminf(fmaxf(un, 0.0f), 1.0f);
                nu[dr][c] = un;
            }
        }
        #pragma unroll
        for (int dr = 0; dr < RPW; ++dr) {
            #pragma unroll
            for (int c = 0; c < 4; ++c)
                u[dr][c] = inimg[dr] ? nu[dr][c] : 0.f;  // out-of-image rows are conv zero-pad
        }
        __syncthreads();  // protect vt/vb from next iteration's writes
    }

    // write back the 32-row core
    #pragma unroll
    for (int dr = 0; dr < RPW; ++dr) {
        const int grow = growbase + dr;
        if (grow >= r0 && grow < r0 + CORE) {
            *reinterpret_cast<float4*>(uout + ubase + (size_t)grow * WW + c0) =
                make_float4(u[dr][0], u[dr][1], u[dr][2], u[dr][3]);
        }
    }
}

extern "C" void kernel_launch(void* const* d_in, const int* in_sizes, int n_in,
                              void* d_out, int out_size, void* d_ws, size_t ws_size,
                              hipStream_t stream) {
    (void)in_sizes; (void)n_in; (void)out_size; (void)ws_size;
    const float* u      = (const float*)d_in[0];
    const float* params = (const float*)d_in[1];
    const int*   t      = (const int*)d_in[2];
    float*       out    = (float*)d_out;
    float*       ws     = (float*)d_ws;

    const dim3 grid(256), block(1024);
    // steps [0,8) -> ws, [8,16) -> out, [16,24) -> ws, [24,31) -> out
    rd_group_kernel<<<grid, block, 0, stream>>>(u,   params, t, ws,  0,  8);
    rd_group_kernel<<<grid, block, 0, stream>>>(ws,  params, t, out, 8,  8);
    rd_group_kernel<<<grid, block, 0, stream>>>(out, params, t, ws,  16, 8);
    rd_group_kernel<<<grid, block, 0, stream>>>(ws,  params, t, out, 24, 7);
}

// Round 3
// 51.630 us; speedup vs baseline: 69.8390x; 1.1633x over previous
//
#include <hip/hip_runtime.h>

#define HH 256
#define WW 256
#define PLANE (HH * WW)          // 65536
#define CORE 32                  // output rows per strip
#define HALO 16                  // temporal halo rows (>= steps per launch)
#define SLAB 64                  // CORE + 2*HALO
#define NW 16                    // waves per block (1024 threads)
#define RPW 4                    // slab rows per wave (SLAB / NW)

// One block = one 64-row slab of one image (32-row core + 16-row halo).
// u, D, rho live in registers (4 rows x 4 cols per thread).
// Horizontal neighbors: wave-internal __shfl (a wave owns a full 256-col row).
// Vertical neighbors across waves: double-buffered LDS rows, ONE barrier/step.
// Runs ls = clamp(t[b]-base, 0, k) steps; halo >= ls keeps the core exact.
// Load skipping: only halo rows within distance ls are needed (params: ls-1);
// unloaded rows start at 0 and their garbage never reaches the core in ls steps.
// Out-of-image rows: u=0, D=rho=0 => u stays 0 forever (= conv zero-padding).
__global__ __launch_bounds__(1024, 4)
void rd_tb16_kernel(const float* __restrict__ uin,
                    const float* __restrict__ params,
                    const int* __restrict__ t,
                    float* __restrict__ uout,
                    int base, int k)
{
    __shared__ float4 vt[2][NW][64];   // each wave's top row (dr=0), double-buffered
    __shared__ float4 vb[2][NW][64];   // each wave's bottom row (dr=RPW-1)

    const int blk   = blockIdx.x;
    const int b     = blk >> 3;          // image index
    const int strip = blk & 7;
    const int r0    = strip * CORE;
    const int w     = threadIdx.x >> 6;  // wave = row-group, 0..15
    const int lane  = threadIdx.x & 63;  // lane = col-group (4 cols each)
    const int c0    = lane << 2;

    int ls = t[b] - base;
    ls = ls < 0 ? 0 : (ls > k ? k : ls);

    const int growbase = r0 - HALO + RPW * w;  // global row of this thread's dr=0
    const size_t ubase = (size_t)b * PLANE;
    const size_t pbase = (size_t)b * 2 * PLANE;

    float u[RPW][4], pD[RPW][4], pR[RPW][4];

    #pragma unroll
    for (int dr = 0; dr < RPW; ++dr) {
        const int grow = growbase + dr;
        const bool inimg = (grow >= 0) && (grow < HH);
        int dist = 0;
        if (grow < r0)             dist = r0 - grow;
        else if (grow > r0 + CORE - 1) dist = grow - (r0 + CORE - 1);
        const bool needU = inimg && (dist <= ls);
        const bool needP = inimg && (dist < ls);   // params only for rows that compute

        if (needU) {
            const float4 uu = *reinterpret_cast<const float4*>(uin + ubase + (size_t)grow * WW + c0);
            u[dr][0] = uu.x; u[dr][1] = uu.y; u[dr][2] = uu.z; u[dr][3] = uu.w;
        } else {
            u[dr][0] = u[dr][1] = u[dr][2] = u[dr][3] = 0.f;
        }
        if (needP) {
            const float4 dd = *reinterpret_cast<const float4*>(params + pbase + (size_t)grow * WW + c0);
            const float4 rr = *reinterpret_cast<const float4*>(params + pbase + PLANE + (size_t)grow * WW + c0);
            pD[dr][0] = dd.x; pD[dr][1] = dd.y; pD[dr][2] = dd.z; pD[dr][3] = dd.w;
            pR[dr][0] = rr.x; pR[dr][1] = rr.y; pR[dr][2] = rr.z; pR[dr][3] = rr.w;
        } else {
            pD[dr][0] = pD[dr][1] = pD[dr][2] = pD[dr][3] = 0.f;
            pR[dr][0] = pR[dr][1] = pR[dr][2] = pR[dr][3] = 0.f;
        }
    }

    if (ls > 0) {
        // publish initial wave-boundary rows into buffer 0
        vt[0][w][lane] = make_float4(u[0][0], u[0][1], u[0][2], u[0][3]);
        vb[0][w][lane] = make_float4(u[RPW-1][0], u[RPW-1][1], u[RPW-1][2], u[RPW-1][3]);

        for (int s = 0; s < ls; ++s) {
            __syncthreads();                 // buf[cur] now visible to all waves
            const int cur = s & 1;

            float upr[4] = {0.f, 0.f, 0.f, 0.f};
            float dnr[4] = {0.f, 0.f, 0.f, 0.f};
            if (w > 0)      { float4 v = vb[cur][w-1][lane]; upr[0]=v.x; upr[1]=v.y; upr[2]=v.z; upr[3]=v.w; }
            if (w < NW - 1) { float4 v = vt[cur][w+1][lane]; dnr[0]=v.x; dnr[1]=v.y; dnr[2]=v.z; dnr[3]=v.w; }

            float nu[RPW][4];
            #pragma unroll
            for (int dr = 0; dr < RPW; ++dr) {
                float lf = __shfl_up(u[dr][3], 1);
                if (lane == 0)  lf = 0.f;
                float rt = __shfl_down(u[dr][0], 1);
                if (lane == 63) rt = 0.f;

                #pragma unroll
                for (int c = 0; c < 4; ++c) {
                    const float upv = dr ? u[dr-1][c] : upr[c];
                    const float dnv = (dr < RPW - 1) ? u[dr+1][c] : dnr[c];
                    const float lv  = c ? u[dr][c-1] : lf;
                    const float rv  = (c < 3) ? u[dr][c+1] : rt;
                    const float uc  = u[dr][c];
                    const float lap = upv + dnv + lv + rv - 4.0f * uc;
                    float un = uc + pD[dr][c] * lap + pR[dr][c] * (uc * (1.0f - uc));
                    nu[dr][c] = fminf(fmaxf(un, 0.0f), 1.0f);
                }
            }
            #pragma unroll
            for (int dr = 0; dr < RPW; ++dr)
                #pragma unroll
                for (int c = 0; c < 4; ++c)
                    u[dr][c] = nu[dr][c];

            // publish updated boundary rows into the other buffer; the barrier
            // at the top of the next iteration orders these against reads.
            const int nxt = cur ^ 1;
            vt[nxt][w][lane] = make_float4(u[0][0], u[0][1], u[0][2], u[0][3]);
            vb[nxt][w][lane] = make_float4(u[RPW-1][0], u[RPW-1][1], u[RPW-1][2], u[RPW-1][3]);
        }
    }

    // write back the 32-row core (waves 4..11 own exactly rows r0..r0+31)
    if (w >= HALO / RPW && w < (HALO + CORE) / RPW) {
        #pragma unroll
        for (int dr = 0; dr < RPW; ++dr) {
            const int grow = growbase + dr;
            *reinterpret_cast<float4*>(uout + ubase + (size_t)grow * WW + c0) =
                make_float4(u[dr][0], u[dr][1], u[dr][2], u[dr][3]);
        }
    }
}

extern "C" void kernel_launch(void* const* d_in, const int* in_sizes, int n_in,
                              void* d_out, int out_size, void* d_ws, size_t ws_size,
                              hipStream_t stream) {
    (void)in_sizes; (void)n_in; (void)out_size; (void)ws_size;
    const float* u      = (const float*)d_in[0];
    const float* params = (const float*)d_in[1];
    const int*   t      = (const int*)d_in[2];
    float*       out    = (float*)d_out;
    float*       ws     = (float*)d_ws;

    const dim3 grid(256), block(1024);
    // steps [0,16) -> ws, steps [16,31) -> out
    rd_tb16_kernel<<<grid, block, 0, stream>>>(u,  params, t, ws,  0,  16);
    rd_tb16_kernel<<<grid, block, 0, stream>>>(ws, params, t, out, 16, 15);
}